// Round 6
// baseline (153.114 us; speedup 1.0000x reference)
//
#include <hip/hip_runtime.h>

// ---------------------------------------------------------------------------
// SparseAttention v5: barrier-free register-direct GEMMs.
// prep(1 kernel) -> QKV GEMM (no LDS, wave-independent 64x64 tiles, register
// double-buffer, zero barriers) -> full-MFMA fused attention -> out GEMM
// (same barrier-free structure).
// B=2 S=2048 D=512 H=8 hd=64, fp32 I/O.
// GEMM math: C=(Ah+Al)*Bh 2-product split-bf16 MFMA (fp32-grade accuracy).
// Rationale: K=512 -> only 16 K-steps; with 1-1.5 blocks/CU the per-step
// vmcnt(0)+barrier drain dominated (R2-R5 evidence). Direct b128 global->VGPR
// fragment loads (Bt stored [n][k], A pre-split) need no LDS and no syncs.
// ---------------------------------------------------------------------------

typedef __bf16 bf16x8 __attribute__((ext_vector_type(8)));
typedef float  f32x4  __attribute__((ext_vector_type(4)));
typedef unsigned short u16;
typedef unsigned int   u32;

__device__ __forceinline__ u16 f2bf(float f) {
  u32 u = __builtin_bit_cast(u32, f);
  u += 0x7FFFu + ((u >> 16) & 1u);
  return (u16)(u >> 16);
}
__device__ __forceinline__ float bf2f(u16 u) {
  return __builtin_bit_cast(float, ((u32)u) << 16);
}
__device__ __forceinline__ u32 pack2(u16 a, u16 b) {
  return (u32)a | ((u32)b << 16);
}
__device__ __forceinline__ f32x4 mfma16(bf16x8 a, bf16x8 b, f32x4 c) {
  return __builtin_amdgcn_mfma_f32_16x16x32_bf16(a, b, c, 0, 0, 0);
}

// ---------------------------------------------------------------------------
// prep_all: one launch. blocks [0,2048): split x into xh/xl.
// [2048,2816): transpose+round w_qkv. [2816,3072): transpose+round w_out.
// ---------------------------------------------------------------------------
__global__ __launch_bounds__(256) void prep_all(
    const float4* __restrict__ X, uint2* __restrict__ XH, uint2* __restrict__ XL,
    const float* __restrict__ Wq, u16* __restrict__ Wqt,
    const float* __restrict__ Wo, u16* __restrict__ Wot) {
  __shared__ float T[32][33];
  const int blk = blockIdx.x, t = threadIdx.x;
  if (blk < 2048) {
    int i = blk * 256 + t;
    float4 v = X[i];
    u16 h0 = f2bf(v.x), h1 = f2bf(v.y), h2 = f2bf(v.z), h3 = f2bf(v.w);
    XH[i] = make_uint2(pack2(h0, h1), pack2(h2, h3));
    XL[i] = make_uint2(pack2(f2bf(v.x - bf2f(h0)), f2bf(v.y - bf2f(h1))),
                       pack2(f2bf(v.z - bf2f(h2)), f2bf(v.w - bf2f(h3))));
    return;
  }
  const float* W;
  u16* Wt;
  int n0, k0, N;
  if (blk < 2816) {
    int idx = blk - 2048;
    W = Wq; Wt = Wqt; N = 1536;
    n0 = (idx % 48) * 32; k0 = (idx / 48) * 32;
  } else {
    int idx = blk - 2816;
    W = Wo; Wt = Wot; N = 512;
    n0 = (idx % 16) * 32; k0 = (idx / 16) * 32;
  }
  const int r = t >> 3, c = (t & 7) * 4;
  float4 v = *(const float4*)&W[(size_t)(k0 + r) * N + n0 + c];
  T[c][r] = v.x; T[c + 1][r] = v.y; T[c + 2][r] = v.z; T[c + 3][r] = v.w;
  __syncthreads();
  u16 a = f2bf(T[r][c]),      b = f2bf(T[r][c + 1]);
  u16 cc = f2bf(T[r][c + 2]), d = f2bf(T[r][c + 3]);
  *(uint2*)&Wt[(size_t)(n0 + r) * 512 + k0 + c] =
      make_uint2(pack2(a, b), pack2(cc, d));
}

// ---------------------------------------------------------------------------
// gemm_qkv_d: [4096,512](split bf16) @ Bt[1536][512] + bias -> Q/K/V bf16.
// No LDS, no barriers. Wave-independent 64x64 tile; per K-step: 12 direct
// b128 fragment loads + 32 MFMA; register prefetch of next step.
// grid (24, 16) x 256thr: wave w covers rows by*256+w*64..+64, cols bx*64.
// ---------------------------------------------------------------------------
__global__ __launch_bounds__(256) void gemm_qkv_d(
    const u16* __restrict__ Ah, const u16* __restrict__ Al,
    const u16* __restrict__ Bt, const float* __restrict__ bias,
    u16* __restrict__ Qb, u16* __restrict__ Kb, u16* __restrict__ Vb) {
  const int t = threadIdx.x, l = t & 63, w = t >> 6;
  const int r15 = l & 15, kg = l >> 4;
  const int mRow0 = blockIdx.y * 256 + w * 64;
  const int nCol0 = blockIdx.x * 64;

  const u16* pA[4];
  const u16* pE[4];
  const u16* pB[4];
#pragma unroll
  for (int mt = 0; mt < 4; ++mt) {
    size_t off = (size_t)(mRow0 + mt * 16 + r15) * 512 + kg * 8;
    pA[mt] = Ah + off;
    pE[mt] = Al + off;
  }
#pragma unroll
  for (int nt = 0; nt < 4; ++nt)
    pB[nt] = Bt + (size_t)(nCol0 + nt * 16 + r15) * 512 + kg * 8;

  f32x4 acc[4][4];
#pragma unroll
  for (int i = 0; i < 4; ++i)
#pragma unroll
    for (int j = 0; j < 4; ++j) acc[i][j] = (f32x4){0.f, 0.f, 0.f, 0.f};

  bf16x8 ca[4], ce[4], cb[4];
#pragma unroll
  for (int i = 0; i < 4; ++i) {
    ca[i] = *(const bf16x8*)(pA[i]);
    ce[i] = *(const bf16x8*)(pE[i]);
    cb[i] = *(const bf16x8*)(pB[i]);
  }
  for (int s = 1; s <= 16; ++s) {
    bf16x8 na[4], ne[4], nb[4];
    if (s < 16) {
      int k0 = s * 32;
#pragma unroll
      for (int i = 0; i < 4; ++i) {
        na[i] = *(const bf16x8*)(pA[i] + k0);
        ne[i] = *(const bf16x8*)(pE[i] + k0);
        nb[i] = *(const bf16x8*)(pB[i] + k0);
      }
    }
#pragma unroll
    for (int mt = 0; mt < 4; ++mt)
#pragma unroll
      for (int nt = 0; nt < 4; ++nt) {
        acc[mt][nt] = mfma16(ca[mt], cb[nt], acc[mt][nt]);
        acc[mt][nt] = mfma16(ce[mt], cb[nt], acc[mt][nt]);
      }
    if (s < 16) {
#pragma unroll
      for (int i = 0; i < 4; ++i) { ca[i] = na[i]; ce[i] = ne[i]; cb[i] = nb[i]; }
    }
  }

  // epilogue: C/D layout col=lane&15, row=(lane>>4)*4+reg. One segment/block.
  const int seg = nCol0 >> 9, cc0 = nCol0 & 511;
  const int lq = l >> 4;
#pragma unroll
  for (int mt = 0; mt < 4; ++mt) {
    int row0 = mRow0 + mt * 16 + lq * 4;
#pragma unroll
    for (int nt = 0; nt < 4; ++nt) {
      int cc = cc0 + nt * 16 + r15;
      float bv = bias[nCol0 + nt * 16 + r15];
      if (seg == 0) {
#pragma unroll
        for (int r = 0; r < 4; ++r)
          Qb[(size_t)(row0 + r) * 512 + cc] = f2bf((acc[mt][nt][r] + bv) * 0.125f);
      } else if (seg == 1) {
#pragma unroll
        for (int r = 0; r < 4; ++r)
          Kb[(size_t)(row0 + r) * 512 + cc] = f2bf(acc[mt][nt][r] + bv);
      } else {
#pragma unroll
        for (int r = 0; r < 4; ++r)
          Vb[(size_t)(row0 + r) * 512 + cc] = f2bf(acc[mt][nt][r] + bv);
      }
    }
  }
}

// ---------------------------------------------------------------------------
// gemm_out_d: [4096,512](split bf16) @ Wot[512][512] + bias -> fp32 out.
// Same barrier-free structure. grid (8, 16) x 256thr.
// ---------------------------------------------------------------------------
__global__ __launch_bounds__(256) void gemm_out_d(
    const u16* __restrict__ Ah, const u16* __restrict__ Al,
    const u16* __restrict__ Bt, const float* __restrict__ bias,
    float* __restrict__ Cf) {
  const int t = threadIdx.x, l = t & 63, w = t >> 6;
  const int r15 = l & 15, kg = l >> 4;
  const int mRow0 = blockIdx.y * 256 + w * 64;
  const int nCol0 = blockIdx.x * 64;

  const u16* pA[4];
  const u16* pE[4];
  const u16* pB[4];
#pragma unroll
  for (int mt = 0; mt < 4; ++mt) {
    size_t off = (size_t)(mRow0 + mt * 16 + r15) * 512 + kg * 8;
    pA[mt] = Ah + off;
    pE[mt] = Al + off;
  }
#pragma unroll
  for (int nt = 0; nt < 4; ++nt)
    pB[nt] = Bt + (size_t)(nCol0 + nt * 16 + r15) * 512 + kg * 8;

  f32x4 acc[4][4];
#pragma unroll
  for (int i = 0; i < 4; ++i)
#pragma unroll
    for (int j = 0; j < 4; ++j) acc[i][j] = (f32x4){0.f, 0.f, 0.f, 0.f};

  bf16x8 ca[4], ce[4], cb[4];
#pragma unroll
  for (int i = 0; i < 4; ++i) {
    ca[i] = *(const bf16x8*)(pA[i]);
    ce[i] = *(const bf16x8*)(pE[i]);
    cb[i] = *(const bf16x8*)(pB[i]);
  }
  for (int s = 1; s <= 16; ++s) {
    bf16x8 na[4], ne[4], nb[4];
    if (s < 16) {
      int k0 = s * 32;
#pragma unroll
      for (int i = 0; i < 4; ++i) {
        na[i] = *(const bf16x8*)(pA[i] + k0);
        ne[i] = *(const bf16x8*)(pE[i] + k0);
        nb[i] = *(const bf16x8*)(pB[i] + k0);
      }
    }
#pragma unroll
    for (int mt = 0; mt < 4; ++mt)
#pragma unroll
      for (int nt = 0; nt < 4; ++nt) {
        acc[mt][nt] = mfma16(ca[mt], cb[nt], acc[mt][nt]);
        acc[mt][nt] = mfma16(ce[mt], cb[nt], acc[mt][nt]);
      }
    if (s < 16) {
#pragma unroll
      for (int i = 0; i < 4; ++i) { ca[i] = na[i]; ce[i] = ne[i]; cb[i] = nb[i]; }
    }
  }

  const int lq = l >> 4;
#pragma unroll
  for (int mt = 0; mt < 4; ++mt) {
    int row0 = mRow0 + mt * 16 + lq * 4;
#pragma unroll
    for (int nt = 0; nt < 4; ++nt) {
      int col = nCol0 + nt * 16 + r15;
      float bv = bias[col];
#pragma unroll
      for (int r = 0; r < 4; ++r)
        Cf[(size_t)(row0 + r) * 512 + col] = acc[mt][nt][r] + bv;
    }
  }
}

// ---------------------------------------------------------------------------
// attn_mfma: per (64-row tile, h, b). QK^T (64x128x64) and PV (64x64x128)
// on matrix cores. Q pre-scaled bf16. Softmax in C-layout via shfl_xor over
// the 16-lane row group. P: C-layout regs -> LDS [s][j] -> A-frag b128.
// Output split h/l bf16 for the out-projection GEMM.
// ---------------------------------------------------------------------------
__global__ __launch_bounds__(256) void attn_mfma(
    const u16* __restrict__ Qb, const u16* __restrict__ Kb,
    const u16* __restrict__ Vb, u16* __restrict__ Oh, u16* __restrict__ Ol) {
  const int tile = blockIdx.x, h = blockIdx.y, b = blockIdx.z;
  const int base = tile * 64;
  const size_t hb = (size_t)b * 2048;

  __shared__ __align__(16) u16 Qs[64][72];    // [s][d]
  __shared__ __align__(16) u16 Ks[128][72];   // [j][d]
  __shared__ __align__(16) u16 Vt[64][136];   // [d][j]
  __shared__ __align__(16) u16 Pp[64][136];   // [s][j]

  const int t = threadIdx.x, l = t & 63, w = t >> 6;
  const int r15 = l & 15, kg = l >> 4;

  // ---- stage Q (row copy) ----
  {
    int r = t >> 2, c0 = (t & 3) * 16;
    const uint4* src = (const uint4*)&Qb[(hb + base + r) * 512 + h * 64 + c0];
    *(uint4*)&Qs[r][c0] = src[0];
    *(uint4*)&Qs[r][c0 + 8] = src[1];
  }
  // ---- stage K (row copy, clamped band) ----
  {
    int j = t >> 1, half = (t & 1) * 32;
    int ja = min(max(base - 32 + j, 0), 2047);
    const uint4* src = (const uint4*)&Kb[(hb + ja) * 512 + h * 64 + half];
    uint4* dst = (uint4*)&Ks[j][half];
    dst[0] = src[0]; dst[1] = src[1]; dst[2] = src[2]; dst[3] = src[3];
  }
  // ---- stage V transposed: Vt[d][j] ----
  {
    int j = t >> 1, ds = (t & 1) * 32;
    int ja = min(max(base - 32 + j, 0), 2047);
    const u16* src = &Vb[(hb + ja) * 512 + h * 64 + ds];
    u16 tmp[32];
    *(uint4*)&tmp[0]  = *(const uint4*)(src);
    *(uint4*)&tmp[8]  = *(const uint4*)(src + 8);
    *(uint4*)&tmp[16] = *(const uint4*)(src + 16);
    *(uint4*)&tmp[24] = *(const uint4*)(src + 24);
#pragma unroll
    for (int i = 0; i < 32; ++i) Vt[ds + i][j] = tmp[i];
  }
  __syncthreads();

  // ---- QK^T: wave w owns rows [w*16, w*16+16) ----
  bf16x8 aQ0 = *(const bf16x8*)&Qs[w * 16 + r15][kg * 8];
  bf16x8 aQ1 = *(const bf16x8*)&Qs[w * 16 + r15][32 + kg * 8];
  f32x4 zero = (f32x4){0.f, 0.f, 0.f, 0.f};
  f32x4 sacc[8];
#pragma unroll
  for (int nt = 0; nt < 8; ++nt) {
    bf16x8 b0 = *(const bf16x8*)&Ks[nt * 16 + r15][kg * 8];
    bf16x8 b1 = *(const bf16x8*)&Ks[nt * 16 + r15][32 + kg * 8];
    sacc[nt] = mfma16(aQ0, b0, zero);
    sacc[nt] = mfma16(aQ1, b1, sacc[nt]);
  }

  // ---- mask + softmax (C-layout: row = w*16+kg*4+r, col = nt*16+r15) ----
#pragma unroll
  for (int r = 0; r < 4; ++r) {
    int s_abs = base + w * 16 + kg * 4 + r;
    float m = -3.0e38f;
#pragma unroll
    for (int nt = 0; nt < 8; ++nt) {
      int j_abs = base - 32 + nt * 16 + r15;
      int dlt = j_abs - s_abs;
      bool valid = (dlt >= -32) && (dlt <= 32) && (j_abs >= 0) && (j_abs < 2048);
      float v = valid ? sacc[nt][r] : -1.0e9f;
      sacc[nt][r] = v;
      m = fmaxf(m, v);
    }
#pragma unroll
    for (int msk = 1; msk < 16; msk <<= 1) m = fmaxf(m, __shfl_xor(m, msk, 64));
    float s_ = 0.f;
#pragma unroll
    for (int nt = 0; nt < 8; ++nt) {
      float e = __expf(sacc[nt][r] - m);
      sacc[nt][r] = e;
      s_ += e;
    }
#pragma unroll
    for (int msk = 1; msk < 16; msk <<= 1) s_ += __shfl_xor(s_, msk, 64);
    float inv = 1.0f / s_;
#pragma unroll
    for (int nt = 0; nt < 8; ++nt)
      Pp[w * 16 + kg * 4 + r][nt * 16 + r15] = f2bf(sacc[nt][r] * inv);
  }
  __syncthreads();

  // ---- PV: O[s][d], K-dim = j (128) ----
  bf16x8 aP[4];
#pragma unroll
  for (int kt = 0; kt < 4; ++kt)
    aP[kt] = *(const bf16x8*)&Pp[w * 16 + r15][kt * 32 + kg * 8];
  f32x4 oacc[4];
#pragma unroll
  for (int nt = 0; nt < 4; ++nt) oacc[nt] = zero;
#pragma unroll
  for (int nt = 0; nt < 4; ++nt) {
#pragma unroll
    for (int kt = 0; kt < 4; ++kt) {
      bf16x8 bV = *(const bf16x8*)&Vt[nt * 16 + r15][kt * 32 + kg * 8];
      oacc[nt] = mfma16(aP[kt], bV, oacc[nt]);
    }
  }

  // ---- epilogue: write O split h/l bf16 ----
#pragma unroll
  for (int nt = 0; nt < 4; ++nt) {
#pragma unroll
    for (int r = 0; r < 4; ++r) {
      float v = oacc[nt][r];
      size_t idx =
          (hb + base + w * 16 + kg * 4 + r) * 512 + h * 64 + nt * 16 + r15;
      u16 hh = f2bf(v);
      Oh[idx] = hh;
      Ol[idx] = f2bf(v - bf2f(hh));
    }
  }
}

// ---------------------------------------------------------------------------
extern "C" void kernel_launch(void* const* d_in, const int* in_sizes, int n_in,
                              void* d_out, int out_size, void* d_ws, size_t ws_size,
                              hipStream_t stream) {
  const float* x     = (const float*)d_in[0];
  const float* w_qkv = (const float*)d_in[1];
  const float* b_qkv = (const float*)d_in[2];
  const float* w_out = (const float*)d_in[3];
  const float* b_out = (const float*)d_in[4];
  float* out = (float*)d_out;

  // workspace layout (~31.5 MB)
  char* ws = (char*)d_ws;
  u16* xh  = (u16*)(ws + 0);          // 4096x512 bf16 = 4194304
  u16* xl  = (u16*)(ws + 4194304);    // 4194304
  u16* wqt = (u16*)(ws + 8388608);    // 1536x512 bf16 = 1572864
  u16* wot = (u16*)(ws + 9961472);    // 512x512 bf16  = 524288
  u16* qb  = (u16*)(ws + 10485760);   // 4096x512 bf16 (pre-scaled) = 4194304
  u16* kb  = (u16*)(ws + 14680064);   // 4194304
  u16* vb  = (u16*)(ws + 18874368);   // 4194304
  u16* aoh = (u16*)(ws + 23068672);   // 4194304
  u16* aol = (u16*)(ws + 27262976);   // 4194304

  prep_all<<<3072, 256, 0, stream>>>((const float4*)x, (uint2*)xh, (uint2*)xl,
                                     w_qkv, wqt, w_out, wot);
  gemm_qkv_d<<<dim3(24, 16), 256, 0, stream>>>(xh, xl, wqt, b_qkv, qb, kb, vb);
  attn_mfma<<<dim3(32, 8, 2), 256, 0, stream>>>(qb, kb, vb, aoh, aol);
  gemm_out_d<<<dim3(8, 16), 256, 0, stream>>>(aoh, aol, wot, b_out, out);
}

// Round 8
// 112.783 us; speedup vs baseline: 1.3576x; 1.3576x over previous
//
#include <hip/hip_runtime.h>

// ---------------------------------------------------------------------------
// SparseAttention v7: v4.1 structure (known-good 117us) + reduced-precision
// out-projection within error budget.
// prep(1 kernel) -> 128x128 glds GEMM (QKV -> Q-scaled/K/V bf16) ->
// full-MFMA fused attention (writes Oh bf16 only) -> single-product out GEMM.
// B=2 S=2048 D=512 H=8 hd=64, fp32 I/O.
// QKV GEMM: C=(Ah+Al)*Bh 2-product split-bf16 MFMA (fp32-grade; needed since
// scores amplify through softmax). Out GEMM: C=Ah*Bh single product — attn-out
// bf16 quantization adds ~3e-4 (budget: measured 9.8e-4 vs 3.24e-3 threshold).
// R6 lesson: direct-fragment global loads scatter-die (52us). R7 lesson:
// hipLaunchCooperativeKernel does not survive this harness. Stay 4-launch.
// ---------------------------------------------------------------------------

typedef __bf16 bf16x8 __attribute__((ext_vector_type(8)));
typedef float  f32x4  __attribute__((ext_vector_type(4)));
typedef unsigned short u16;
typedef unsigned int   u32;

__device__ __forceinline__ u16 f2bf(float f) {
  u32 u = __builtin_bit_cast(u32, f);
  u += 0x7FFFu + ((u >> 16) & 1u);
  return (u16)(u >> 16);
}
__device__ __forceinline__ float bf2f(u16 u) {
  return __builtin_bit_cast(float, ((u32)u) << 16);
}
__device__ __forceinline__ u32 pack2(u16 a, u16 b) {
  return (u32)a | ((u32)b << 16);
}
__device__ __forceinline__ void glds16(const void* g, void* l) {
  __builtin_amdgcn_global_load_lds(
      (const __attribute__((address_space(1))) void*)g,
      (__attribute__((address_space(3))) void*)l, 16, 0, 0);
}
__device__ __forceinline__ f32x4 mfma16(bf16x8 a, bf16x8 b, f32x4 c) {
  return __builtin_amdgcn_mfma_f32_16x16x32_bf16(a, b, c, 0, 0, 0);
}

// ---------------------------------------------------------------------------
// prep_all: blocks [0,2048): split x into xh/xl. [2048,2816): transpose+round
// w_qkv. [2816,3072): transpose+round w_out.
// ---------------------------------------------------------------------------
__global__ __launch_bounds__(256) void prep_all(
    const float4* __restrict__ X, uint2* __restrict__ XH, uint2* __restrict__ XL,
    const float* __restrict__ Wq, u16* __restrict__ Wqt,
    const float* __restrict__ Wo, u16* __restrict__ Wot) {
  __shared__ float T[32][33];
  const int blk = blockIdx.x, t = threadIdx.x;
  if (blk < 2048) {
    int i = blk * 256 + t;
    float4 v = X[i];
    u16 h0 = f2bf(v.x), h1 = f2bf(v.y), h2 = f2bf(v.z), h3 = f2bf(v.w);
    XH[i] = make_uint2(pack2(h0, h1), pack2(h2, h3));
    XL[i] = make_uint2(pack2(f2bf(v.x - bf2f(h0)), f2bf(v.y - bf2f(h1))),
                       pack2(f2bf(v.z - bf2f(h2)), f2bf(v.w - bf2f(h3))));
    return;
  }
  const float* W;
  u16* Wt;
  int n0, k0, N;
  if (blk < 2816) {
    int idx = blk - 2048;
    W = Wq; Wt = Wqt; N = 1536;
    n0 = (idx % 48) * 32; k0 = (idx / 48) * 32;
  } else {
    int idx = blk - 2816;
    W = Wo; Wt = Wot; N = 512;
    n0 = (idx % 16) * 32; k0 = (idx / 16) * 32;
  }
  const int r = t >> 3, c = (t & 7) * 4;
  float4 v = *(const float4*)&W[(size_t)(k0 + r) * N + n0 + c];
  T[c][r] = v.x; T[c + 1][r] = v.y; T[c + 2][r] = v.z; T[c + 3][r] = v.w;
  __syncthreads();
  u16 a = f2bf(T[r][c]),      b = f2bf(T[r][c + 1]);
  u16 cc = f2bf(T[r][c + 2]), d = f2bf(T[r][c + 3]);
  *(uint2*)&Wt[(size_t)(n0 + r) * 512 + k0 + c] =
      make_uint2(pack2(a, b), pack2(cc, d));
}

// ---------------------------------------------------------------------------
// gemm_qkv: [4096,512](split) @ [512,1536]^T(bf16) + bias.
// 128x128 tile, BK=32, 4 waves 2x2, wave 64x64 = 4x4 mfma, 32 MFMA/wave/iter.
// Epilogue: col<512 -> Qb bf16 *0.125 ; <1024 -> Kb bf16 ; else Vb bf16.
// ---------------------------------------------------------------------------
__global__ __launch_bounds__(256) void gemm_qkv(
    const u16* __restrict__ Ah, const u16* __restrict__ Al,
    const u16* __restrict__ Bt, const float* __restrict__ bias,
    u16* __restrict__ Qb, u16* __restrict__ Kb, u16* __restrict__ Vb) {
  __shared__ __align__(16) u16 sAh[128 * 32];
  __shared__ __align__(16) u16 sAl[128 * 32];
  __shared__ __align__(16) u16 sB[128 * 32];

  const int t = threadIdx.x, l = t & 63, w = t >> 6;
  const int wm = w >> 1, wn = w & 1;
  const int mBase = blockIdx.y * 128, nBase = blockIdx.x * 128;

  const int q = l >> 2;
  const int kq = ((l & 3) ^ ((q >> 1) & 3)) * 8;
  const int rw0 = w * 32 + q, rw1 = rw0 + 16;
  const u16* gAh0 = Ah + (size_t)(mBase + rw0) * 512 + kq;
  const u16* gAh1 = Ah + (size_t)(mBase + rw1) * 512 + kq;
  const u16* gAl0 = Al + (size_t)(mBase + rw0) * 512 + kq;
  const u16* gAl1 = Al + (size_t)(mBase + rw1) * 512 + kq;
  const u16* gB0  = Bt + (size_t)(nBase + rw0) * 512 + kq;
  const u16* gB1  = Bt + (size_t)(nBase + rw1) * 512 + kq;
  u16* lAh0 = sAh + (w * 32) * 32;
  u16* lAh1 = sAh + (w * 32 + 16) * 32;
  u16* lAl0 = sAl + (w * 32) * 32;
  u16* lAl1 = sAl + (w * 32 + 16) * 32;
  u16* lB0  = sB + (w * 32) * 32;
  u16* lB1  = sB + (w * 32 + 16) * 32;

  const int r15 = l & 15, kg = l >> 4;
  const int pq = (kg ^ ((r15 >> 1) & 3)) * 8;
  int aoff[4], boff[4];
#pragma unroll
  for (int mt = 0; mt < 4; ++mt) aoff[mt] = (wm * 64 + mt * 16 + r15) * 32 + pq;
#pragma unroll
  for (int nt = 0; nt < 4; ++nt) boff[nt] = (wn * 64 + nt * 16 + r15) * 32 + pq;

  f32x4 acc[4][4];
#pragma unroll
  for (int i = 0; i < 4; ++i)
#pragma unroll
    for (int j = 0; j < 4; ++j) acc[i][j] = (f32x4){0.f, 0.f, 0.f, 0.f};

  for (int k0 = 0; k0 < 512; k0 += 32) {
    glds16(gAh0 + k0, lAh0);
    glds16(gAh1 + k0, lAh1);
    glds16(gAl0 + k0, lAl0);
    glds16(gAl1 + k0, lAl1);
    glds16(gB0 + k0, lB0);
    glds16(gB1 + k0, lB1);
    __syncthreads();
    bf16x8 b[4];
#pragma unroll
    for (int nt = 0; nt < 4; ++nt) b[nt] = *(const bf16x8*)(sB + boff[nt]);
#pragma unroll
    for (int mt = 0; mt < 4; ++mt) {
      bf16x8 ah = *(const bf16x8*)(sAh + aoff[mt]);
      bf16x8 al = *(const bf16x8*)(sAl + aoff[mt]);
#pragma unroll
      for (int nt = 0; nt < 4; ++nt) {
        acc[mt][nt] = mfma16(ah, b[nt], acc[mt][nt]);
        acc[mt][nt] = mfma16(al, b[nt], acc[mt][nt]);
      }
    }
    __syncthreads();
  }

  const int lq = l >> 4;
  const int seg = nBase >> 9, colb = nBase & 511;
#pragma unroll
  for (int mt = 0; mt < 4; ++mt) {
    int row0 = mBase + wm * 64 + mt * 16 + lq * 4;
#pragma unroll
    for (int nt = 0; nt < 4; ++nt) {
      int col = wn * 64 + nt * 16 + r15;
      float bv = bias[nBase + col];
      int cc = colb + col;
      if (seg == 0) {
#pragma unroll
        for (int r = 0; r < 4; ++r)
          Qb[(size_t)(row0 + r) * 512 + cc] = f2bf((acc[mt][nt][r] + bv) * 0.125f);
      } else if (seg == 1) {
#pragma unroll
        for (int r = 0; r < 4; ++r)
          Kb[(size_t)(row0 + r) * 512 + cc] = f2bf(acc[mt][nt][r] + bv);
      } else {
#pragma unroll
        for (int r = 0; r < 4; ++r)
          Vb[(size_t)(row0 + r) * 512 + cc] = f2bf(acc[mt][nt][r] + bv);
      }
    }
  }
}

// ---------------------------------------------------------------------------
// attn_mfma: per (64-row tile, h, b). QK^T and PV on matrix cores.
// Writes attention output as bf16 (Oh only — single-product out-GEMM).
// ---------------------------------------------------------------------------
__global__ __launch_bounds__(256) void attn_mfma(
    const u16* __restrict__ Qb, const u16* __restrict__ Kb,
    const u16* __restrict__ Vb, u16* __restrict__ Oh) {
  const int tile = blockIdx.x, h = blockIdx.y, b = blockIdx.z;
  const int base = tile * 64;
  const size_t hb = (size_t)b * 2048;

  __shared__ __align__(16) u16 Qs[64][72];    // [s][d]
  __shared__ __align__(16) u16 Ks[128][72];   // [j][d]
  __shared__ __align__(16) u16 Vt[64][136];   // [d][j]
  __shared__ __align__(16) u16 Pp[64][136];   // [s][j]

  const int t = threadIdx.x, l = t & 63, w = t >> 6;
  const int r15 = l & 15, kg = l >> 4;

  // stage Q
  {
    int r = t >> 2, c0 = (t & 3) * 16;
    const uint4* src = (const uint4*)&Qb[(hb + base + r) * 512 + h * 64 + c0];
    *(uint4*)&Qs[r][c0] = src[0];
    *(uint4*)&Qs[r][c0 + 8] = src[1];
  }
  // stage K (clamped band)
  {
    int j = t >> 1, half = (t & 1) * 32;
    int ja = min(max(base - 32 + j, 0), 2047);
    const uint4* src = (const uint4*)&Kb[(hb + ja) * 512 + h * 64 + half];
    uint4* dst = (uint4*)&Ks[j][half];
    dst[0] = src[0]; dst[1] = src[1]; dst[2] = src[2]; dst[3] = src[3];
  }
  // stage V transposed
  {
    int j = t >> 1, ds = (t & 1) * 32;
    int ja = min(max(base - 32 + j, 0), 2047);
    const u16* src = &Vb[(hb + ja) * 512 + h * 64 + ds];
    u16 tmp[32];
    *(uint4*)&tmp[0]  = *(const uint4*)(src);
    *(uint4*)&tmp[8]  = *(const uint4*)(src + 8);
    *(uint4*)&tmp[16] = *(const uint4*)(src + 16);
    *(uint4*)&tmp[24] = *(const uint4*)(src + 24);
#pragma unroll
    for (int i = 0; i < 32; ++i) Vt[ds + i][j] = tmp[i];
  }
  __syncthreads();

  // QK^T: wave w owns rows [w*16, w*16+16)
  bf16x8 aQ0 = *(const bf16x8*)&Qs[w * 16 + r15][kg * 8];
  bf16x8 aQ1 = *(const bf16x8*)&Qs[w * 16 + r15][32 + kg * 8];
  f32x4 zero = (f32x4){0.f, 0.f, 0.f, 0.f};
  f32x4 sacc[8];
#pragma unroll
  for (int nt = 0; nt < 8; ++nt) {
    bf16x8 b0 = *(const bf16x8*)&Ks[nt * 16 + r15][kg * 8];
    bf16x8 b1 = *(const bf16x8*)&Ks[nt * 16 + r15][32 + kg * 8];
    sacc[nt] = mfma16(aQ0, b0, zero);
    sacc[nt] = mfma16(aQ1, b1, sacc[nt]);
  }

  // mask + softmax (C-layout: row = w*16+kg*4+r, col = nt*16+r15)
#pragma unroll
  for (int r = 0; r < 4; ++r) {
    int s_abs = base + w * 16 + kg * 4 + r;
    float m = -3.0e38f;
#pragma unroll
    for (int nt = 0; nt < 8; ++nt) {
      int j_abs = base - 32 + nt * 16 + r15;
      int dlt = j_abs - s_abs;
      bool valid = (dlt >= -32) && (dlt <= 32) && (j_abs >= 0) && (j_abs < 2048);
      float v = valid ? sacc[nt][r] : -1.0e9f;
      sacc[nt][r] = v;
      m = fmaxf(m, v);
    }
#pragma unroll
    for (int msk = 1; msk < 16; msk <<= 1) m = fmaxf(m, __shfl_xor(m, msk, 64));
    float s_ = 0.f;
#pragma unroll
    for (int nt = 0; nt < 8; ++nt) {
      float e = __expf(sacc[nt][r] - m);
      sacc[nt][r] = e;
      s_ += e;
    }
#pragma unroll
    for (int msk = 1; msk < 16; msk <<= 1) s_ += __shfl_xor(s_, msk, 64);
    float inv = 1.0f / s_;
#pragma unroll
    for (int nt = 0; nt < 8; ++nt)
      Pp[w * 16 + kg * 4 + r][nt * 16 + r15] = f2bf(sacc[nt][r] * inv);
  }
  __syncthreads();

  // PV
  bf16x8 aP[4];
#pragma unroll
  for (int kt = 0; kt < 4; ++kt)
    aP[kt] = *(const bf16x8*)&Pp[w * 16 + r15][kt * 32 + kg * 8];
  f32x4 oacc[4];
#pragma unroll
  for (int nt = 0; nt < 4; ++nt) oacc[nt] = zero;
#pragma unroll
  for (int nt = 0; nt < 4; ++nt) {
#pragma unroll
    for (int kt = 0; kt < 4; ++kt) {
      bf16x8 bV = *(const bf16x8*)&Vt[nt * 16 + r15][kt * 32 + kg * 8];
      oacc[nt] = mfma16(aP[kt], bV, oacc[nt]);
    }
  }

  // epilogue: write O as bf16 (single-product out-GEMM downstream)
#pragma unroll
  for (int nt = 0; nt < 4; ++nt) {
#pragma unroll
    for (int r = 0; r < 4; ++r) {
      size_t idx =
          (hb + base + w * 16 + kg * 4 + r) * 512 + h * 64 + nt * 16 + r15;
      Oh[idx] = f2bf(oacc[nt][r]);
    }
  }
}

// ---------------------------------------------------------------------------
// gemm_out: [4096,512](bf16) @ [512,512]^T(bf16) + bias -> fp32 out.
// Single-product. 64x128 tile, grid (4,64) = 256 blocks. LDS 12KB.
// ---------------------------------------------------------------------------
__global__ __launch_bounds__(256) void gemm_out(
    const u16* __restrict__ Ah, const u16* __restrict__ Bt,
    const float* __restrict__ bias, float* __restrict__ Cf) {
  __shared__ __align__(16) u16 sAh[64 * 32];
  __shared__ __align__(16) u16 sB[128 * 32];

  const int t = threadIdx.x, l = t & 63, w = t >> 6;
  const int wm = w >> 1, wn = w & 1;
  const int mBase = blockIdx.y * 64, nBase = blockIdx.x * 128;

  const int q = l >> 2;
  const int kq = ((l & 3) ^ ((q >> 1) & 3)) * 8;
  const int rA = w * 16 + q;
  const u16* gAh = Ah + (size_t)(mBase + rA) * 512 + kq;
  const u16* gB0 = Bt + (size_t)(nBase + rA) * 512 + kq;
  const u16* gB1 = Bt + (size_t)(nBase + 64 + rA) * 512 + kq;
  u16* lAh = sAh + w * 512;
  u16* lB0 = sB + w * 512;
  u16* lB1 = sB + (w + 4) * 512;

  const int r15 = l & 15, kg = l >> 4;
  const int pq = (kg ^ ((r15 >> 1) & 3)) * 8;
  const int aoff0 = (wm * 32 + r15) * 32 + pq;
  const int aoff1 = aoff0 + 16 * 32;
  int boff[4];
#pragma unroll
  for (int nt = 0; nt < 4; ++nt) boff[nt] = (wn * 64 + nt * 16 + r15) * 32 + pq;

  f32x4 acc[2][4];
#pragma unroll
  for (int i = 0; i < 2; ++i)
#pragma unroll
    for (int j = 0; j < 4; ++j) acc[i][j] = (f32x4){0.f, 0.f, 0.f, 0.f};

  for (int k0 = 0; k0 < 512; k0 += 32) {
    glds16(gAh + k0, lAh);
    glds16(gB0 + k0, lB0);
    glds16(gB1 + k0, lB1);
    __syncthreads();
    bf16x8 a0 = *(const bf16x8*)(sAh + aoff0);
    bf16x8 a1 = *(const bf16x8*)(sAh + aoff1);
#pragma unroll
    for (int nt = 0; nt < 4; ++nt) {
      bf16x8 bb = *(const bf16x8*)(sB + boff[nt]);
      acc[0][nt] = mfma16(a0, bb, acc[0][nt]);
      acc[1][nt] = mfma16(a1, bb, acc[1][nt]);
    }
    __syncthreads();
  }

  const int lq = l >> 4;
#pragma unroll
  for (int mt = 0; mt < 2; ++mt) {
    int row0 = mBase + wm * 32 + mt * 16 + lq * 4;
#pragma unroll
    for (int nt = 0; nt < 4; ++nt) {
      int col = nBase + wn * 64 + nt * 16 + r15;
      float bv = bias[col];
#pragma unroll
      for (int r = 0; r < 4; ++r)
        Cf[(size_t)(row0 + r) * 512 + col] = acc[mt][nt][r] + bv;
    }
  }
}

// ---------------------------------------------------------------------------
extern "C" void kernel_launch(void* const* d_in, const int* in_sizes, int n_in,
                              void* d_out, int out_size, void* d_ws, size_t ws_size,
                              hipStream_t stream) {
  const float* x     = (const float*)d_in[0];
  const float* w_qkv = (const float*)d_in[1];
  const float* b_qkv = (const float*)d_in[2];
  const float* w_out = (const float*)d_in[3];
  const float* b_out = (const float*)d_in[4];
  float* out = (float*)d_out;

  // workspace layout (~27.3 MB)
  char* ws = (char*)d_ws;
  u16* xh  = (u16*)(ws + 0);          // 4096x512 bf16 = 4194304
  u16* xl  = (u16*)(ws + 4194304);    // 4194304
  u16* wqt = (u16*)(ws + 8388608);    // 1536x512 bf16 = 1572864
  u16* wot = (u16*)(ws + 9961472);    // 512x512 bf16  = 524288
  u16* qb  = (u16*)(ws + 10485760);   // 4096x512 bf16 (pre-scaled) = 4194304
  u16* kb  = (u16*)(ws + 14680064);   // 4194304
  u16* vb  = (u16*)(ws + 18874368);   // 4194304
  u16* aoh = (u16*)(ws + 23068672);   // 4194304

  prep_all<<<3072, 256, 0, stream>>>((const float4*)x, (uint2*)xh, (uint2*)xl,
                                     w_qkv, wqt, w_out, wot);
  gemm_qkv<<<dim3(12, 32), 256, 0, stream>>>(xh, xl, wqt, b_qkv, qb, kb, vb);
  attn_mfma<<<dim3(32, 8, 2), 256, 0, stream>>>(qb, kb, vb, aoh);
  gemm_out<<<dim3(4, 64), 256, 0, stream>>>(aoh, wot, b_out, out);
}